// Round 1
// baseline (301.951 us; speedup 1.0000x reference)
//
#include <hip/hip_runtime.h>
#include <hip/hip_bf16.h>
#include <stdint.h>

typedef unsigned short u16;
typedef unsigned int   u32;
typedef __attribute__((ext_vector_type(8))) __bf16 bf16x8;
typedef __attribute__((ext_vector_type(4))) float  f32x4;

#define B_  4
#define S_  1024
#define D_  1024
#define H_  16
#define AD_ 64

__device__ __forceinline__ u16 f2bf(float f) {
    u32 u = __float_as_uint(f);
    u32 r = u + 0x7fffu + ((u >> 16) & 1u);   // RNE
    return (u16)(r >> 16);
}
__device__ __forceinline__ u32 pack2(float a, float b) {
    return (u32)f2bf(a) | ((u32)f2bf(b) << 16);
}
__device__ __forceinline__ float bf2f(u16 h) {
    return __uint_as_float((u32)h << 16);
}

// ---------------------------------------------------------------------------
// Kernel 1: QKV = iQ @ Wa^T + ba  (M=4096, N=3072, K=1024), scatter to
// q [B,H,S,64] bf16 (scaled by 0.125), k [B,H,S,64] bf16, v [B,H,64,S] bf16.
// 128x128 tile, 256 threads (4 waves, 2x2 of 64x64), BK=64, XOR-swizzled LDS.
// ---------------------------------------------------------------------------
__global__ __launch_bounds__(256) void qkv_gemm(
    const float* __restrict__ A, const float* __restrict__ W,
    const float* __restrict__ bias,
    u16* __restrict__ qb, u16* __restrict__ kb, u16* __restrict__ vb)
{
    __shared__ u16 As[128 * 64];
    __shared__ u16 Bs[128 * 64];

    const int tid  = threadIdx.x;
    const int lane = tid & 63, w = tid >> 6;
    const int quad = lane >> 4, ln = lane & 15;
    const int wrow = (w >> 1) * 64, wcol = (w & 1) * 64;
    const int row0 = blockIdx.y * 128, col0 = blockIdx.x * 128;

    f32x4 acc[4][4];
#pragma unroll
    for (int i = 0; i < 4; i++)
#pragma unroll
        for (int j = 0; j < 4; j++) acc[i][j] = (f32x4){0.f, 0.f, 0.f, 0.f};

    const int cr = tid >> 3;   // staging row (step 32 per rep)
    const int cc = tid & 7;    // staging chunk (8 elems)

    for (int kb_i = 0; kb_i < 16; ++kb_i) {
        const int k0 = kb_i * 64;
#pragma unroll
        for (int rep = 0; rep < 4; ++rep) {
            int r = cr + rep * 32;
            const float* sa = A + (size_t)(row0 + r) * D_ + k0 + cc * 8;
            const float* sb = W + (size_t)(col0 + r) * D_ + k0 + cc * 8;
            float4 a0 = *(const float4*)sa;
            float4 a1 = *(const float4*)(sa + 4);
            float4 b0 = *(const float4*)sb;
            float4 b1 = *(const float4*)(sb + 4);
            u32 pa[4] = {pack2(a0.x, a0.y), pack2(a0.z, a0.w),
                         pack2(a1.x, a1.y), pack2(a1.z, a1.w)};
            u32 pb[4] = {pack2(b0.x, b0.y), pack2(b0.z, b0.w),
                         pack2(b1.x, b1.y), pack2(b1.z, b1.w)};
            int c = cc ^ (r & 7);
            *(uint4*)&As[r * 64 + c * 8] = *(uint4*)pa;
            *(uint4*)&Bs[r * 64 + c * 8] = *(uint4*)pb;
        }
        __syncthreads();
#pragma unroll
        for (int ks = 0; ks < 2; ++ks) {
            bf16x8 af[4], bfr[4];
#pragma unroll
            for (int mt = 0; mt < 4; ++mt) {
                int r = wrow + mt * 16 + ln;
                af[mt] = *(bf16x8*)&As[r * 64 + (((ks * 4 + quad) ^ (r & 7)) << 3)];
            }
#pragma unroll
            for (int nt = 0; nt < 4; ++nt) {
                int r = wcol + nt * 16 + ln;
                bfr[nt] = *(bf16x8*)&Bs[r * 64 + (((ks * 4 + quad) ^ (r & 7)) << 3)];
            }
#pragma unroll
            for (int mt = 0; mt < 4; ++mt)
#pragma unroll
                for (int nt = 0; nt < 4; ++nt)
                    acc[mt][nt] = __builtin_amdgcn_mfma_f32_16x16x32_bf16(
                        af[mt], bfr[nt], acc[mt][nt], 0, 0, 0);
        }
        __syncthreads();
    }

    // epilogue: scatter to q/k/v. 'which' is block-uniform (128 | 1024).
    const int which = col0 >> 10;
#pragma unroll
    for (int mt = 0; mt < 4; ++mt) {
#pragma unroll
        for (int nt = 0; nt < 4; ++nt) {
            int n = col0 + wcol + nt * 16 + ln;
            float bv = bias[n];
            int h = (n >> 6) & 15, d = n & 63;
#pragma unroll
            for (int reg = 0; reg < 4; ++reg) {
                int m = row0 + wrow + mt * 16 + quad * 4 + reg;
                int b = m >> 10, s = m & 1023;
                float v = acc[mt][nt][reg] + bv;
                if (which == 0) {
                    qb[((size_t)((b * 16 + h) * 1024 + s)) * 64 + d] = f2bf(v * 0.125f);
                } else if (which == 1) {
                    kb[((size_t)((b * 16 + h) * 1024 + s)) * 64 + d] = f2bf(v);
                } else {
                    vb[((size_t)((b * 16 + h) * 64 + d)) * 1024 + s] = f2bf(v);
                }
            }
        }
    }
}

// ---------------------------------------------------------------------------
// Kernel 2: fused attention. One block per (b,h, 64-row q-tile).
// SparseNormer: t = relu(s + snb)^2; attn = t / (sum_j t + eps).
// No online rescaling needed — accumulate unnormalized O and row sums L.
// ---------------------------------------------------------------------------
__global__ __launch_bounds__(256) void attn_kernel(
    const u16* __restrict__ qb, const u16* __restrict__ kb,
    const u16* __restrict__ vb, const float* __restrict__ rel,
    const float* __restrict__ snb_p, u16* __restrict__ ctx)
{
    __shared__ u16 q_s[64 * 64];
    __shared__ u16 k_s[64 * 64];
    __shared__ u16 v_s[64 * 64];
    __shared__ u16 t_s[64 * 72];        // 144B rows (pad 8) -> 16B aligned b128
    __shared__ float qr[64 * 33];

    const int tid  = threadIdx.x;
    const int lane = tid & 63, w = tid >> 6;
    const int quad = lane >> 4, ln = lane & 15;
    const int wrow = w * 16;
    const int bh = blockIdx.x >> 4, qt = blockIdx.x & 15;
    const int i0 = qt * 64;
    const float snb = snb_p[0];

    const u16* qplane = qb + ((size_t)bh * 1024 + i0) * 64;
    const u16* kplane = kb + (size_t)bh * 1024 * 64;
    const u16* vplane = vb + (size_t)bh * 64 * 1024;

    const int cr = tid >> 3, cc = tid & 7;

    // stage q tile (swizzled)
#pragma unroll
    for (int rep = 0; rep < 2; ++rep) {
        int r = cr + rep * 32;
        uint4 val = *(const uint4*)(qplane + (size_t)r * 64 + cc * 8);
        *(uint4*)&q_s[r * 64 + ((cc ^ (r & 7)) << 3)] = val;
    }
    __syncthreads();

    // qrel[i][p] = q[i,:] . rel_emb[p,:]   (q already scaled by 0.125)
    for (int idx = tid; idx < 64 * 33; idx += 256) {
        int i = idx / 33, p = idx - i * 33;
        float s = 0.f;
#pragma unroll
        for (int d = 0; d < 64; ++d) {
            float qv = bf2f(q_s[i * 64 + (((d >> 3) ^ (i & 7)) << 3) + (d & 7)]);
            s += qv * rel[p * 64 + d];
        }
        qr[idx] = s;
    }

    float Lrow[4] = {0.f, 0.f, 0.f, 0.f};   // per-lane partial row sums
    f32x4 o_acc[4];
#pragma unroll
    for (int nt = 0; nt < 4; ++nt) o_acc[nt] = (f32x4){0.f, 0.f, 0.f, 0.f};

    for (int jt = 0; jt < 16; ++jt) {
        const int j0 = jt * 64;
        __syncthreads();   // prev iter readers done (first iter: qr ready)
#pragma unroll
        for (int rep = 0; rep < 2; ++rep) {
            int r = cr + rep * 32;
            uint4 kv = *(const uint4*)(kplane + (size_t)(j0 + r) * 64 + cc * 8);
            *(uint4*)&k_s[r * 64 + ((cc ^ (r & 7)) << 3)] = kv;
            uint4 vv = *(const uint4*)(vplane + (size_t)r * 1024 + j0 + cc * 8);
            *(uint4*)&v_s[r * 64 + ((cc ^ (r & 7)) << 3)] = vv;
        }
        __syncthreads();

        // S tile: wave computes rows wrow..wrow+15 x 64 cols
        f32x4 sacc[4];
#pragma unroll
        for (int nt = 0; nt < 4; ++nt) sacc[nt] = (f32x4){0.f, 0.f, 0.f, 0.f};
#pragma unroll
        for (int ks = 0; ks < 2; ++ks) {
            int rq = wrow + ln;
            bf16x8 aq = *(bf16x8*)&q_s[rq * 64 + (((ks * 4 + quad) ^ (rq & 7)) << 3)];
#pragma unroll
            for (int nt = 0; nt < 4; ++nt) {
                int rk = nt * 16 + ln;
                bf16x8 bk = *(bf16x8*)&k_s[rk * 64 + (((ks * 4 + quad) ^ (rk & 7)) << 3)];
                sacc[nt] = __builtin_amdgcn_mfma_f32_16x16x32_bf16(aq, bk, sacc[nt], 0, 0, 0);
            }
        }

        // rel bias + SparseNormer numerator; write t (bf16) to LDS
#pragma unroll
        for (int nt = 0; nt < 4; ++nt) {
#pragma unroll
            for (int reg = 0; reg < 4; ++reg) {
                int iloc = wrow + quad * 4 + reg;
                int jloc = nt * 16 + ln;
                int dlt = (j0 + jloc) - (i0 + iloc);
                int p = dlt < -16 ? 0 : (dlt > 16 ? 32 : dlt + 16);
                float sv = sacc[nt][reg] + qr[iloc * 33 + p] + snb;
                float t = fmaxf(sv, 0.f);
                t = t * t;
                Lrow[reg] += t;                       // lane-partial over j
                t_s[iloc * 72 + jloc] = f2bf(t);
            }
        }
        // PV: own-wave t rows, no barrier needed (lgkmcnt orders within wave)
#pragma unroll
        for (int ks = 0; ks < 2; ++ks) {
            int rt = wrow + ln;
            bf16x8 at = *(bf16x8*)&t_s[rt * 72 + ks * 32 + quad * 8];
#pragma unroll
            for (int nt = 0; nt < 4; ++nt) {
                int rv = nt * 16 + ln;
                bf16x8 bv = *(bf16x8*)&v_s[rv * 64 + (((ks * 4 + quad) ^ (rv & 7)) << 3)];
                o_acc[nt] = __builtin_amdgcn_mfma_f32_16x16x32_bf16(at, bv, o_acc[nt], 0, 0, 0);
            }
        }
    }

    // reduce row sums across the 16 lanes of each quad
    float Linv[4];
#pragma unroll
    for (int reg = 0; reg < 4; ++reg) {
        float rs = Lrow[reg];
        rs += __shfl_xor(rs, 1);
        rs += __shfl_xor(rs, 2);
        rs += __shfl_xor(rs, 4);
        rs += __shfl_xor(rs, 8);
        Linv[reg] = 1.f / (rs + 1e-8f);
    }
    const int b = bh >> 4, h = bh & 15;
#pragma unroll
    for (int nt = 0; nt < 4; ++nt) {
        int dg = nt * 16 + ln;
#pragma unroll
        for (int reg = 0; reg < 4; ++reg) {
            int ig = i0 + wrow + quad * 4 + reg;
            float ov = o_acc[nt][reg] * Linv[reg];
            ctx[((size_t)(b * 1024 + ig)) * 1024 + h * 64 + dg] = f2bf(ov);
        }
    }
}

// ---------------------------------------------------------------------------
// Kernel 3: out = ctx @ Wo^T + bo  (M=4096, N=1024, K=1024), fp32 out.
// ---------------------------------------------------------------------------
__global__ __launch_bounds__(256) void out_gemm(
    const u16* __restrict__ A, const float* __restrict__ W,
    const float* __restrict__ bias, float* __restrict__ out)
{
    __shared__ u16 As[128 * 64];
    __shared__ u16 Bs[128 * 64];

    const int tid  = threadIdx.x;
    const int lane = tid & 63, w = tid >> 6;
    const int quad = lane >> 4, ln = lane & 15;
    const int wrow = (w >> 1) * 64, wcol = (w & 1) * 64;
    const int row0 = blockIdx.y * 128, col0 = blockIdx.x * 128;

    f32x4 acc[4][4];
#pragma unroll
    for (int i = 0; i < 4; i++)
#pragma unroll
        for (int j = 0; j < 4; j++) acc[i][j] = (f32x4){0.f, 0.f, 0.f, 0.f};

    const int cr = tid >> 3;
    const int cc = tid & 7;

    for (int kb_i = 0; kb_i < 16; ++kb_i) {
        const int k0 = kb_i * 64;
#pragma unroll
        for (int rep = 0; rep < 4; ++rep) {
            int r = cr + rep * 32;
            uint4 av = *(const uint4*)(A + (size_t)(row0 + r) * D_ + k0 + cc * 8);
            const float* sb = W + (size_t)(col0 + r) * D_ + k0 + cc * 8;
            float4 b0 = *(const float4*)sb;
            float4 b1 = *(const float4*)(sb + 4);
            u32 pb[4] = {pack2(b0.x, b0.y), pack2(b0.z, b0.w),
                         pack2(b1.x, b1.y), pack2(b1.z, b1.w)};
            int c = cc ^ (r & 7);
            *(uint4*)&As[r * 64 + c * 8] = av;
            *(uint4*)&Bs[r * 64 + c * 8] = *(uint4*)pb;
        }
        __syncthreads();
#pragma unroll
        for (int ks = 0; ks < 2; ++ks) {
            bf16x8 af[4], bfr[4];
#pragma unroll
            for (int mt = 0; mt < 4; ++mt) {
                int r = wrow + mt * 16 + ln;
                af[mt] = *(bf16x8*)&As[r * 64 + (((ks * 4 + quad) ^ (r & 7)) << 3)];
            }
#pragma unroll
            for (int nt = 0; nt < 4; ++nt) {
                int r = wcol + nt * 16 + ln;
                bfr[nt] = *(bf16x8*)&Bs[r * 64 + (((ks * 4 + quad) ^ (r & 7)) << 3)];
            }
#pragma unroll
            for (int mt = 0; mt < 4; ++mt)
#pragma unroll
                for (int nt = 0; nt < 4; ++nt)
                    acc[mt][nt] = __builtin_amdgcn_mfma_f32_16x16x32_bf16(
                        af[mt], bfr[nt], acc[mt][nt], 0, 0, 0);
        }
        __syncthreads();
    }
#pragma unroll
    for (int mt = 0; mt < 4; ++mt) {
#pragma unroll
        for (int nt = 0; nt < 4; ++nt) {
            int n = col0 + wcol + nt * 16 + ln;
            float bv = bias[n];
#pragma unroll
            for (int reg = 0; reg < 4; ++reg) {
                int m = row0 + wrow + mt * 16 + quad * 4 + reg;
                out[(size_t)m * D_ + n] = acc[mt][nt][reg] + bv;
            }
        }
    }
}

// ---------------------------------------------------------------------------
extern "C" void kernel_launch(void* const* d_in, const int* in_sizes, int n_in,
                              void* d_out, int out_size, void* d_ws, size_t ws_size,
                              hipStream_t stream)
{
    const float* iQ  = (const float*)d_in[0];
    const float* Wa  = (const float*)d_in[1];
    const float* ba  = (const float*)d_in[2];
    const float* rel = (const float*)d_in[3];
    const float* snb = (const float*)d_in[4];
    const float* Wo  = (const float*)d_in[5];
    const float* bo  = (const float*)d_in[6];
    float* out = (float*)d_out;

    const size_t PLANE = (size_t)B_ * H_ * S_ * AD_;   // 4M elems
    u16* qbuf = (u16*)d_ws;
    u16* kbuf = qbuf + PLANE;
    u16* vbuf = kbuf + PLANE;
    u16* ctx  = vbuf + PLANE;

    qkv_gemm<<<dim3(24, 32), 256, 0, stream>>>(iQ, Wa, ba, qbuf, kbuf, vbuf);
    attn_kernel<<<dim3(1024), 256, 0, stream>>>(qbuf, kbuf, vbuf, rel, snb, ctx);
    out_gemm<<<dim3(8, 32), 256, 0, stream>>>(ctx, Wo, bo, out);
}

// Round 2
// 201.605 us; speedup vs baseline: 1.4977x; 1.4977x over previous
//
#include <hip/hip_runtime.h>
#include <hip/hip_bf16.h>
#include <stdint.h>

typedef unsigned short u16;
typedef unsigned int   u32;
typedef __attribute__((ext_vector_type(8))) __bf16 bf16x8;
typedef __attribute__((ext_vector_type(4))) float  f32x4;
typedef __attribute__((ext_vector_type(2))) u32    u32x2;

#define B_  4
#define S_  1024
#define D_  1024
#define H_  16
#define AD_ 64

#if defined(__has_builtin)
#if __has_builtin(__builtin_amdgcn_cvt_pk_bf16_f32)
#define HAVE_CVT_PK 1
#endif
#endif

#ifdef HAVE_CVT_PK
typedef __attribute__((ext_vector_type(2))) __bf16 bf16x2;
__device__ __forceinline__ u32 pack2(float a, float b) {
    bf16x2 r = __builtin_amdgcn_cvt_pk_bf16_f32(a, b);
    return __builtin_bit_cast(u32, r);
}
__device__ __forceinline__ u16 f2bf(float f) {
    return (u16)pack2(f, f);
}
#else
__device__ __forceinline__ u16 f2bf(float f) {
    u32 u = __float_as_uint(f);
    u32 r = u + 0x7fffu + ((u >> 16) & 1u);   // RNE
    return (u16)(r >> 16);
}
__device__ __forceinline__ u32 pack2(float a, float b) {
    return (u32)f2bf(a) | ((u32)f2bf(b) << 16);
}
#endif

// ---------------------------------------------------------------------------
// Kernel 0: fp32 -> bf16 pre-conversion of iQ, Wa, Wo (memory-bound, ~8us)
// ---------------------------------------------------------------------------
__global__ __launch_bounds__(256) void conv_bf16(
    const float* __restrict__ a, const float* __restrict__ b,
    const float* __restrict__ c,
    u16* __restrict__ ao, u16* __restrict__ bo, u16* __restrict__ co,
    int na, int nb)
{
    int gid = blockIdx.x * 256 + threadIdx.x;
    int base = gid * 8;
    const float* src; u16* dst; int off;
    if (base < na)           { src = a; dst = ao; off = base; }
    else if (base < na + nb) { src = b; dst = bo; off = base - na; }
    else                     { src = c; dst = co; off = base - na - nb; }
    float4 v0 = *(const float4*)(src + off);
    float4 v1 = *(const float4*)(src + off + 4);
    u32 pk[4] = {pack2(v0.x, v0.y), pack2(v0.z, v0.w),
                 pack2(v1.x, v1.y), pack2(v1.z, v1.w)};
    *(uint4*)(dst + off) = *(uint4*)pk;
}

// ---------------------------------------------------------------------------
// Kernel 1: QKV = iQ @ Wa^T + ba  (M=4096, N=3072, K=1024), bf16 inputs.
// Scatter q (x0.125) [B,H,S,64], k [B,H,S,64], v transposed [B,H,64,S].
// ---------------------------------------------------------------------------
__global__ __launch_bounds__(256) void qkv_gemm(
    const u16* __restrict__ A, const u16* __restrict__ W,
    const float* __restrict__ bias,
    u16* __restrict__ qb, u16* __restrict__ kb, u16* __restrict__ vb)
{
    __shared__ u16 As[128 * 64];
    __shared__ u16 Bs[128 * 64];

    const int tid  = threadIdx.x;
    const int lane = tid & 63, w = tid >> 6;
    const int quad = lane >> 4, ln = lane & 15;
    const int wrow = (w >> 1) * 64, wcol = (w & 1) * 64;
    const int row0 = blockIdx.y * 128, col0 = blockIdx.x * 128;

    f32x4 acc[4][4];
#pragma unroll
    for (int i = 0; i < 4; i++)
#pragma unroll
        for (int j = 0; j < 4; j++) acc[i][j] = (f32x4){0.f, 0.f, 0.f, 0.f};

    const int cr = tid >> 3;   // 0..31
    const int cc = tid & 7;

    for (int kb_i = 0; kb_i < 16; ++kb_i) {
        const int k0 = kb_i * 64;
#pragma unroll
        for (int rep = 0; rep < 4; ++rep) {
            int r = cr + rep * 32;
            uint4 av = *(const uint4*)(A + (size_t)(row0 + r) * D_ + k0 + cc * 8);
            uint4 bv = *(const uint4*)(W + (size_t)(col0 + r) * D_ + k0 + cc * 8);
            int c = cc ^ (r & 7);
            *(uint4*)&As[r * 64 + c * 8] = av;
            *(uint4*)&Bs[r * 64 + c * 8] = bv;
        }
        __syncthreads();
#pragma unroll
        for (int ks = 0; ks < 2; ++ks) {
            bf16x8 af[4], bfr[4];
#pragma unroll
            for (int mt = 0; mt < 4; ++mt) {
                int r = wrow + mt * 16 + ln;
                af[mt] = *(bf16x8*)&As[r * 64 + (((ks * 4 + quad) ^ (r & 7)) << 3)];
            }
#pragma unroll
            for (int nt = 0; nt < 4; ++nt) {
                int r = wcol + nt * 16 + ln;
                bfr[nt] = *(bf16x8*)&Bs[r * 64 + (((ks * 4 + quad) ^ (r & 7)) << 3)];
            }
#pragma unroll
            for (int mt = 0; mt < 4; ++mt)
#pragma unroll
                for (int nt = 0; nt < 4; ++nt)
                    acc[mt][nt] = __builtin_amdgcn_mfma_f32_16x16x32_bf16(
                        af[mt], bfr[nt], acc[mt][nt], 0, 0, 0);
        }
        __syncthreads();
    }

    const int which = col0 >> 10;   // block-uniform: 0=q, 1=k, 2=v
#pragma unroll
    for (int mt = 0; mt < 4; ++mt) {
#pragma unroll
        for (int nt = 0; nt < 4; ++nt) {
            int n = col0 + wcol + nt * 16 + ln;
            float bv = bias[n];
            int h = (n >> 6) & 15, d = n & 63;
            if (which == 2) {
                // v: 4 consecutive s per lane -> packed 8B store
                int m0 = row0 + wrow + mt * 16 + quad * 4;
                int b = m0 >> 10, s0 = m0 & 1023;
                u32x2 pk;
                pk.x = pack2(acc[mt][nt][0] + bv, acc[mt][nt][1] + bv);
                pk.y = pack2(acc[mt][nt][2] + bv, acc[mt][nt][3] + bv);
                *(u32x2*)&vb[((size_t)((b * 16 + h) * 64 + d)) * 1024 + s0] = pk;
            } else {
#pragma unroll
                for (int reg = 0; reg < 4; ++reg) {
                    int m = row0 + wrow + mt * 16 + quad * 4 + reg;
                    int b = m >> 10, s = m & 1023;
                    float v = acc[mt][nt][reg] + bv;
                    if (which == 0)
                        qb[((size_t)((b * 16 + h) * 1024 + s)) * 64 + d] = f2bf(v * 0.125f);
                    else
                        kb[((size_t)((b * 16 + h) * 1024 + s)) * 64 + d] = f2bf(v);
                }
            }
        }
    }
}

// ---------------------------------------------------------------------------
// Kernel 2: fused attention, S^T formulation.
// Wave w owns i-strip [w*16, w*16+16). QK^T computed transposed (D[j][i]) so
// each lane has i = lane&15 fixed: far-field rel bias is a per-lane constant,
// L-sum is one scalar per lane, t packs as b64 writes.
// ---------------------------------------------------------------------------
__global__ __launch_bounds__(256) void attn_kernel(
    const u16* __restrict__ qb, const u16* __restrict__ kb,
    const u16* __restrict__ vb, const float* __restrict__ rel,
    const float* __restrict__ snb_p, u16* __restrict__ ctx)
{
    __shared__ u16 q_s[64 * 64];
    __shared__ u16 k_s[64 * 64];
    __shared__ u16 v_s[64 * 64];
    __shared__ u16 t_s[64 * 64];        // overlays rel staging (48*64 <= 64*64)
    __shared__ float qr[33 * 64];       // [p][i_local]

    u16* rel_s = t_s;

    const int tid  = threadIdx.x;
    const int lane = tid & 63, w = tid >> 6;
    const int quad = lane >> 4, ln = lane & 15;
    const int strip = w * 16;
    const int bh = blockIdx.x >> 4, qt = blockIdx.x & 15;
    const int i0 = qt * 64;
    const float snb = snb_p[0];

    const u16* qplane = qb + ((size_t)bh * 1024 + i0) * 64;
    const u16* kplane = kb + (size_t)bh * 1024 * 64;
    const u16* vplane = vb + (size_t)bh * 64 * 1024;

    const int cr = tid >> 3, cc = tid & 7;

    // stage q tile (swizzled)
#pragma unroll
    for (int rep = 0; rep < 2; ++rep) {
        int r = cr + rep * 32;
        uint4 val = *(const uint4*)(qplane + (size_t)r * 64 + cc * 8);
        *(uint4*)&q_s[r * 64 + ((cc ^ (r & 7)) << 3)] = val;
    }
    // stage rel (33 rows + zero pad to 48), bf16 swizzled
    for (int idx = tid; idx < 384; idx += 256) {
        int p = idx >> 3, c = idx & 7;
        u32 pk[4];
        if (p < 33) {
            const float* sp = rel + p * 64 + c * 8;
            float4 r0 = *(const float4*)sp;
            float4 r1 = *(const float4*)(sp + 4);
            pk[0] = pack2(r0.x, r0.y); pk[1] = pack2(r0.z, r0.w);
            pk[2] = pack2(r1.x, r1.y); pk[3] = pack2(r1.z, r1.w);
        } else { pk[0] = pk[1] = pk[2] = pk[3] = 0; }
        *(uint4*)&rel_s[p * 64 + ((c ^ (p & 7)) << 3)] = *(uint4*)pk;
    }
    __syncthreads();

    // qr[p][i] = q[i]·rel[p] via MFMA (a=q rows m=i, b=rel rows n=p)
    {
        f32x4 qacc[3];
#pragma unroll
        for (int nt = 0; nt < 3; ++nt) qacc[nt] = (f32x4){0.f, 0.f, 0.f, 0.f};
#pragma unroll
        for (int ks = 0; ks < 2; ++ks) {
            int rq = strip + ln;
            bf16x8 aq = *(bf16x8*)&q_s[rq * 64 + (((ks * 4 + quad) ^ (rq & 7)) << 3)];
#pragma unroll
            for (int nt = 0; nt < 3; ++nt) {
                int rp = nt * 16 + ln;
                bf16x8 bp = *(bf16x8*)&rel_s[rp * 64 + (((ks * 4 + quad) ^ (rp & 7)) << 3)];
                qacc[nt] = __builtin_amdgcn_mfma_f32_16x16x32_bf16(aq, bp, qacc[nt], 0, 0, 0);
            }
        }
#pragma unroll
        for (int nt = 0; nt < 3; ++nt) {
            int p = nt * 16 + ln;
            if (p < 33) {
#pragma unroll
                for (int reg = 0; reg < 4; ++reg)
                    qr[p * 64 + strip + quad * 4 + reg] = qacc[nt][reg];
            }
        }
    }
    __syncthreads();   // qr complete; rel_s reads done (t_s overlay safe)

    const int iloc = strip + ln;            // this lane's i (local)
    const float cL = qr[iloc] + snb;        // far-left bias  (p=0)
    const float cR = qr[32 * 64 + iloc] + snb;   // far-right (p=32)

    // q fragments for QK (B operand, n=i) are jt-invariant
    bf16x8 bq[2];
#pragma unroll
    for (int ks = 0; ks < 2; ++ks)
        bq[ks] = *(bf16x8*)&q_s[iloc * 64 + (((ks * 4 + quad) ^ (iloc & 7)) << 3)];

    float Lsum = 0.f;
    f32x4 o_acc[4];
#pragma unroll
    for (int nt = 0; nt < 4; ++nt) o_acc[nt] = (f32x4){0.f, 0.f, 0.f, 0.f};

    for (int jt = 0; jt < 16; ++jt) {
        const int j0 = jt * 64;
        __syncthreads();   // prev-iter k_s/v_s readers done
#pragma unroll
        for (int rep = 0; rep < 2; ++rep) {
            int r = cr + rep * 32;
            uint4 kv = *(const uint4*)(kplane + (size_t)(j0 + r) * 64 + cc * 8);
            *(uint4*)&k_s[r * 64 + ((cc ^ (r & 7)) << 3)] = kv;
            uint4 vv = *(const uint4*)(vplane + (size_t)r * 1024 + j0 + cc * 8);
            *(uint4*)&v_s[r * 64 + ((cc ^ (r & 7)) << 3)] = vv;
        }
        __syncthreads();

        // S^T: sacc[mj] = D[j = mj*16+quad*4+reg][i = ln]
        f32x4 sacc[4];
#pragma unroll
        for (int mj = 0; mj < 4; ++mj) sacc[mj] = (f32x4){0.f, 0.f, 0.f, 0.f};
#pragma unroll
        for (int ks = 0; ks < 2; ++ks) {
#pragma unroll
            for (int mj = 0; mj < 4; ++mj) {
                int rk = mj * 16 + ln;
                bf16x8 ak = *(bf16x8*)&k_s[rk * 64 + (((ks * 4 + quad) ^ (rk & 7)) << 3)];
                sacc[mj] = __builtin_amdgcn_mfma_f32_16x16x32_bf16(ak, bq[ks], sacc[mj], 0, 0, 0);
            }
        }

        // epilogue: t = relu(s + bias)^2, pack 4 consecutive j -> b64 write
        const int d0 = j0 - i0;
        if (d0 <= -128 || d0 >= 128) {
            const float c = (d0 < 0) ? cL : cR;    // per-lane constant
#pragma unroll
            for (int mj = 0; mj < 4; ++mj) {
                float tv[4];
#pragma unroll
                for (int reg = 0; reg < 4; ++reg) {
                    float t = fmaxf(sacc[mj][reg] + c, 0.f);
                    t = t * t;
                    Lsum += t;
                    tv[reg] = t;
                }
                u32x2 pk;
                pk.x = pack2(tv[0], tv[1]);
                pk.y = pack2(tv[2], tv[3]);
                int jl = mj * 16 + quad * 4;
                int chunk = (jl >> 3) ^ (iloc & 7);
                *(u32x2*)&t_s[iloc * 64 + (chunk << 3) + (quad & 1) * 4] = pk;
            }
        } else {
#pragma unroll
            for (int mj = 0; mj < 4; ++mj) {
                int jbase = j0 + mj * 16 + quad * 4;
                float tv[4];
#pragma unroll
                for (int reg = 0; reg < 4; ++reg) {
                    int dlt = jbase + reg - (i0 + iloc);
                    int p = min(max(dlt, -16), 16) + 16;
                    float t = fmaxf(sacc[mj][reg] + qr[p * 64 + iloc] + snb, 0.f);
                    t = t * t;
                    Lsum += t;
                    tv[reg] = t;
                }
                u32x2 pk;
                pk.x = pack2(tv[0], tv[1]);
                pk.y = pack2(tv[2], tv[3]);
                int jl = mj * 16 + quad * 4;
                int chunk = (jl >> 3) ^ (iloc & 7);
                *(u32x2*)&t_s[iloc * 64 + (chunk << 3) + (quad & 1) * 4] = pk;
            }
        }

        // PV: A = t rows (own-wave rows; within-wave DS order, no barrier)
#pragma unroll
        for (int ks = 0; ks < 2; ++ks) {
            bf16x8 at = *(bf16x8*)&t_s[iloc * 64 + (((ks * 4 + quad) ^ (iloc & 7)) << 3)];
#pragma unroll
            for (int nt = 0; nt < 4; ++nt) {
                int rv = nt * 16 + ln;
                bf16x8 bv = *(bf16x8*)&v_s[rv * 64 + (((ks * 4 + quad) ^ (rv & 7)) << 3)];
                o_acc[nt] = __builtin_amdgcn_mfma_f32_16x16x32_bf16(at, bv, o_acc[nt], 0, 0, 0);
            }
        }
    }

    // L lives per-lane at i = strip + ln; sum over the 4 quads holding same i
    Lsum += __shfl_xor(Lsum, 16);
    Lsum += __shfl_xor(Lsum, 32);
    float Linv = 1.f / (Lsum + 1e-8f);

    const int b = bh >> 4, h = bh & 15;
#pragma unroll
    for (int reg = 0; reg < 4; ++reg) {
        int ig = i0 + strip + quad * 4 + reg;
        float li = __shfl(Linv, quad * 4 + reg);   // redistribute to output rows
#pragma unroll
        for (int nt = 0; nt < 4; ++nt) {
            int dg = nt * 16 + ln;
            ctx[((size_t)(b * 1024 + ig)) * 1024 + h * 64 + dg] =
                f2bf(o_acc[nt][reg] * li);
        }
    }
}

// ---------------------------------------------------------------------------
// Kernel 3: out = ctx @ Wo^T + bo  (M=4096, N=1024, K=1024), bf16 in, fp32 out
// ---------------------------------------------------------------------------
__global__ __launch_bounds__(256) void out_gemm(
    const u16* __restrict__ A, const u16* __restrict__ W,
    const float* __restrict__ bias, float* __restrict__ out)
{
    __shared__ u16 As[128 * 64];
    __shared__ u16 Bs[128 * 64];

    const int tid  = threadIdx.x;
    const int lane = tid & 63, w = tid >> 6;
    const int quad = lane >> 4, ln = lane & 15;
    const int wrow = (w >> 1) * 64, wcol = (w & 1) * 64;
    const int row0 = blockIdx.y * 128, col0 = blockIdx.x * 128;

    f32x4 acc[4][4];
#pragma unroll
    for (int i = 0; i < 4; i++)
#pragma unroll
        for (int j = 0; j < 4; j++) acc[i][j] = (f32x4){0.f, 0.f, 0.f, 0.f};

    const int cr = tid >> 3;
    const int cc = tid & 7;

    for (int kb_i = 0; kb_i < 16; ++kb_i) {
        const int k0 = kb_i * 64;
#pragma unroll
        for (int rep = 0; rep < 4; ++rep) {
            int r = cr + rep * 32;
            uint4 av = *(const uint4*)(A + (size_t)(row0 + r) * D_ + k0 + cc * 8);
            uint4 bv = *(const uint4*)(W + (size_t)(col0 + r) * D_ + k0 + cc * 8);
            int c = cc ^ (r & 7);
            *(uint4*)&As[r * 64 + c * 8] = av;
            *(uint4*)&Bs[r * 64 + c * 8] = bv;
        }
        __syncthreads();
#pragma unroll
        for (int ks = 0; ks < 2; ++ks) {
            bf16x8 af[4], bfr[4];
#pragma unroll
            for (int mt = 0; mt < 4; ++mt) {
                int r = wrow + mt * 16 + ln;
                af[mt] = *(bf16x8*)&As[r * 64 + (((ks * 4 + quad) ^ (r & 7)) << 3)];
            }
#pragma unroll
            for (int nt = 0; nt < 4; ++nt) {
                int r = wcol + nt * 16 + ln;
                bfr[nt] = *(bf16x8*)&Bs[r * 64 + (((ks * 4 + quad) ^ (r & 7)) << 3)];
            }
#pragma unroll
            for (int mt = 0; mt < 4; ++mt)
#pragma unroll
                for (int nt = 0; nt < 4; ++nt)
                    acc[mt][nt] = __builtin_amdgcn_mfma_f32_16x16x32_bf16(
                        af[mt], bfr[nt], acc[mt][nt], 0, 0, 0);
        }
        __syncthreads();
    }
#pragma unroll
    for (int mt = 0; mt < 4; ++mt) {
#pragma unroll
        for (int nt = 0; nt < 4; ++nt) {
            int n = col0 + wcol + nt * 16 + ln;
            float bv = bias[n];
#pragma unroll
            for (int reg = 0; reg < 4; ++reg) {
                int m = row0 + wrow + mt * 16 + quad * 4 + reg;
                out[(size_t)m * D_ + n] = acc[mt][nt][reg] + bv;
            }
        }
    }
}

// ---------------------------------------------------------------------------
extern "C" void kernel_launch(void* const* d_in, const int* in_sizes, int n_in,
                              void* d_out, int out_size, void* d_ws, size_t ws_size,
                              hipStream_t stream)
{
    const float* iQ  = (const float*)d_in[0];
    const float* Wa  = (const float*)d_in[1];
    const float* ba  = (const float*)d_in[2];
    const float* rel = (const float*)d_in[3];
    const float* snb = (const float*)d_in[4];
    const float* Wo  = (const float*)d_in[5];
    const float* bo  = (const float*)d_in[6];
    float* out = (float*)d_out;

    const size_t NQ = (size_t)B_ * S_ * D_;     // 4M
    const size_t NWA = (size_t)3 * D_ * D_;     // 3M
    const size_t NWO = (size_t)D_ * D_;         // 1M
    const size_t PLANE = (size_t)B_ * H_ * S_ * AD_;  // 4M

    u16* iQbf = (u16*)d_ws;          // 4M  (reused as ctx after qkv_gemm)
    u16* Wabf = iQbf + NQ;           // 3M
    u16* Wobf = Wabf + NWA;          // 1M
    u16* qbuf = Wobf + NWO;          // 4M
    u16* kbuf = qbuf + PLANE;        // 4M
    u16* vbuf = kbuf + PLANE;        // 4M
    u16* ctx  = iQbf;                // alias: iQbf dead after qkv_gemm

    conv_bf16<<<4096, 256, 0, stream>>>(iQ, Wa, Wo, iQbf, Wabf, Wobf,
                                        (int)NQ, (int)NWA);
    qkv_gemm<<<dim3(24, 32), 256, 0, stream>>>(iQbf, Wabf, ba, qbuf, kbuf, vbuf);
    attn_kernel<<<dim3(1024), 256, 0, stream>>>(qbuf, kbuf, vbuf, rel, snb, ctx);
    out_gemm<<<dim3(8, 32), 256, 0, stream>>>(ctx, Wobf, bo, out);
}

// Round 3
// 196.655 us; speedup vs baseline: 1.5354x; 1.0252x over previous
//
#include <hip/hip_runtime.h>
#include <hip/hip_bf16.h>
#include <stdint.h>

typedef unsigned short u16;
typedef unsigned int   u32;
typedef __attribute__((ext_vector_type(8))) __bf16 bf16x8;
typedef __attribute__((ext_vector_type(4))) float  f32x4;
typedef __attribute__((ext_vector_type(2))) u32    u32x2;

#define B_  4
#define S_  1024
#define D_  1024
#define H_  16
#define AD_ 64

#if defined(__has_builtin)
#if __has_builtin(__builtin_amdgcn_cvt_pk_bf16_f32)
#define HAVE_CVT_PK 1
#endif
#if __has_builtin(__builtin_amdgcn_global_load_lds)
#define HAVE_GLL 1
#endif
#endif

#ifdef HAVE_CVT_PK
typedef __attribute__((ext_vector_type(2))) __bf16 bf16x2;
__device__ __forceinline__ u32 pack2(float a, float b) {
    bf16x2 r = __builtin_amdgcn_cvt_pk_bf16_f32(a, b);
    return __builtin_bit_cast(u32, r);
}
__device__ __forceinline__ u16 f2bf(float f) {
    return (u16)pack2(f, f);
}
#else
__device__ __forceinline__ u16 f2bf(float f) {
    u32 u = __float_as_uint(f);
    u32 r = u + 0x7fffu + ((u >> 16) & 1u);   // RNE
    return (u16)(r >> 16);
}
__device__ __forceinline__ u32 pack2(float a, float b) {
    return (u32)f2bf(a) | ((u32)f2bf(b) << 16);
}
#endif

// Async global->LDS, 16B per lane. LDS dest = base + lane*16 (wave-uniform
// base). Source swizzle (chunk ^ row&7) preserves the LDS XOR layout.
typedef __attribute__((address_space(1))) const u32 gas_u32;
typedef __attribute__((address_space(3))) u32 las_u32;
__device__ __forceinline__ void gll16(const void* g, void* l) {
#ifdef HAVE_GLL
    __builtin_amdgcn_global_load_lds((gas_u32*)g, (las_u32*)l, 16, 0, 0);
#else
    // fallback: synchronous copy (lane-local dest reconstruction)
    int lane = threadIdx.x & 63;
    *(uint4*)((u16*)l + lane * 8) = *(const uint4*)g;
#endif
}

// ---------------------------------------------------------------------------
// Kernel 0: fp32 -> bf16 pre-conversion of iQ, Wa, Wo (memory-bound)
// ---------------------------------------------------------------------------
__global__ __launch_bounds__(256) void conv_bf16(
    const float* __restrict__ a, const float* __restrict__ b,
    const float* __restrict__ c,
    u16* __restrict__ ao, u16* __restrict__ bo, u16* __restrict__ co,
    int na, int nb)
{
    int gid = blockIdx.x * 256 + threadIdx.x;
    int base = gid * 8;
    const float* src; u16* dst; int off;
    if (base < na)           { src = a; dst = ao; off = base; }
    else if (base < na + nb) { src = b; dst = bo; off = base - na; }
    else                     { src = c; dst = co; off = base - na - nb; }
    float4 v0 = *(const float4*)(src + off);
    float4 v1 = *(const float4*)(src + off + 4);
    u32 pk[4] = {pack2(v0.x, v0.y), pack2(v0.z, v0.w),
                 pack2(v1.x, v1.y), pack2(v1.z, v1.w)};
    *(uint4*)(dst + off) = *(uint4*)pk;
}

// ---------------------------------------------------------------------------
// Kernel 1: QKV = iQ @ Wa^T + ba  (M=4096, N=3072, K=1024), bf16 inputs.
// Scatter q (x0.125) [B,H,S,64], k [B,H,S,64], v transposed [B,H,64,S].
// Staging: global_load_lds 16B with source-side XOR swizzle.
// ---------------------------------------------------------------------------
__global__ __launch_bounds__(256) void qkv_gemm(
    const u16* __restrict__ A, const u16* __restrict__ W,
    const float* __restrict__ bias,
    u16* __restrict__ qb, u16* __restrict__ kb, u16* __restrict__ vb)
{
    __shared__ u16 As[128 * 64];
    __shared__ u16 Bs[128 * 64];

    const int tid  = threadIdx.x;
    const int lane = tid & 63, w = tid >> 6;
    const int quad = lane >> 4, ln = lane & 15;
    const int wrow = (w >> 1) * 64, wcol = (w & 1) * 64;
    const int row0 = blockIdx.y * 128, col0 = blockIdx.x * 128;

    const int ri = lane >> 3, ci = lane & 7;          // 8-row staging group
    const int scol = (ci ^ ri) << 3;                  // swizzled source chunk

    f32x4 acc[4][4];
#pragma unroll
    for (int i = 0; i < 4; i++)
#pragma unroll
        for (int j = 0; j < 4; j++) acc[i][j] = (f32x4){0.f, 0.f, 0.f, 0.f};

    for (int kb_i = 0; kb_i < 16; ++kb_i) {
        const int k0 = kb_i * 64;
#pragma unroll
        for (int c = 0; c < 4; ++c) {
            int r0 = c * 32 + w * 8;                  // r0 % 8 == 0
            int gr = r0 + ri;
            gll16(A + (size_t)(row0 + gr) * D_ + k0 + scol, &As[r0 * 64]);
            gll16(W + (size_t)(col0 + gr) * D_ + k0 + scol, &Bs[r0 * 64]);
        }
        __syncthreads();
#pragma unroll
        for (int ks = 0; ks < 2; ++ks) {
            bf16x8 af[4], bfr[4];
#pragma unroll
            for (int mt = 0; mt < 4; ++mt) {
                int r = wrow + mt * 16 + ln;
                af[mt] = *(bf16x8*)&As[r * 64 + (((ks * 4 + quad) ^ (r & 7)) << 3)];
            }
#pragma unroll
            for (int nt = 0; nt < 4; ++nt) {
                int r = wcol + nt * 16 + ln;
                bfr[nt] = *(bf16x8*)&Bs[r * 64 + (((ks * 4 + quad) ^ (r & 7)) << 3)];
            }
#pragma unroll
            for (int mt = 0; mt < 4; ++mt)
#pragma unroll
                for (int nt = 0; nt < 4; ++nt)
                    acc[mt][nt] = __builtin_amdgcn_mfma_f32_16x16x32_bf16(
                        af[mt], bfr[nt], acc[mt][nt], 0, 0, 0);
        }
        __syncthreads();
    }

    const int which = col0 >> 10;   // block-uniform: 0=q, 1=k, 2=v
#pragma unroll
    for (int mt = 0; mt < 4; ++mt) {
#pragma unroll
        for (int nt = 0; nt < 4; ++nt) {
            int n = col0 + wcol + nt * 16 + ln;
            float bv = bias[n];
            int h = (n >> 6) & 15, d = n & 63;
            if (which == 2) {
                int m0 = row0 + wrow + mt * 16 + quad * 4;
                int b = m0 >> 10, s0 = m0 & 1023;
                u32x2 pk;
                pk.x = pack2(acc[mt][nt][0] + bv, acc[mt][nt][1] + bv);
                pk.y = pack2(acc[mt][nt][2] + bv, acc[mt][nt][3] + bv);
                *(u32x2*)&vb[((size_t)((b * 16 + h) * 64 + d)) * 1024 + s0] = pk;
            } else {
#pragma unroll
                for (int reg = 0; reg < 4; ++reg) {
                    int m = row0 + wrow + mt * 16 + quad * 4 + reg;
                    int b = m >> 10, s = m & 1023;
                    float v = acc[mt][nt][reg] + bv;
                    if (which == 0)
                        qb[((size_t)((b * 16 + h) * 1024 + s)) * 64 + d] = f2bf(v * 0.125f);
                    else
                        kb[((size_t)((b * 16 + h) * 1024 + s)) * 64 + d] = f2bf(v);
                }
            }
        }
    }
}

// ---------------------------------------------------------------------------
// Kernel 2: fused attention, S^T formulation (lane's i fixed = lane&15).
// ---------------------------------------------------------------------------
__global__ __launch_bounds__(256) void attn_kernel(
    const u16* __restrict__ qb, const u16* __restrict__ kb,
    const u16* __restrict__ vb, const float* __restrict__ rel,
    const float* __restrict__ snb_p, u16* __restrict__ ctx)
{
    __shared__ u16 q_s[64 * 64];
    __shared__ u16 k_s[64 * 64];
    __shared__ u16 v_s[64 * 64];
    __shared__ u16 t_s[64 * 64];        // overlays rel staging (48*64 <= 64*64)
    __shared__ float qr[33 * 64];       // [p][i_local]

    u16* rel_s = t_s;

    const int tid  = threadIdx.x;
    const int lane = tid & 63, w = tid >> 6;
    const int quad = lane >> 4, ln = lane & 15;
    const int strip = w * 16;
    const int bh = blockIdx.x >> 4, qt = blockIdx.x & 15;
    const int i0 = qt * 64;
    const float snb = snb_p[0];

    const u16* qplane = qb + ((size_t)bh * 1024 + i0) * 64;
    const u16* kplane = kb + (size_t)bh * 1024 * 64;
    const u16* vplane = vb + (size_t)bh * 64 * 1024;

    const int ri = lane >> 3, ci = lane & 7;
    const int scol = (ci ^ ri) << 3;

    // stage q tile: wave w covers rows w*16..w*16+16 (2 calls)
#pragma unroll
    for (int c = 0; c < 2; ++c) {
        int r0 = w * 16 + c * 8;
        int gr = r0 + ri;
        gll16(qplane + (size_t)gr * 64 + scol, &q_s[r0 * 64]);
    }
    // stage rel (33 rows + zero pad to 48), bf16 swizzled (once, VALU ok)
    for (int idx = tid; idx < 384; idx += 256) {
        int p = idx >> 3, c = idx & 7;
        u32 pk[4];
        if (p < 33) {
            const float* sp = rel + p * 64 + c * 8;
            float4 r0 = *(const float4*)sp;
            float4 r1 = *(const float4*)(sp + 4);
            pk[0] = pack2(r0.x, r0.y); pk[1] = pack2(r0.z, r0.w);
            pk[2] = pack2(r1.x, r1.y); pk[3] = pack2(r1.z, r1.w);
        } else { pk[0] = pk[1] = pk[2] = pk[3] = 0; }
        *(uint4*)&rel_s[p * 64 + ((c ^ (p & 7)) << 3)] = *(uint4*)pk;
    }
    __syncthreads();

    // qr[p][i] = q[i]·rel[p] via MFMA
    {
        f32x4 qacc[3];
#pragma unroll
        for (int nt = 0; nt < 3; ++nt) qacc[nt] = (f32x4){0.f, 0.f, 0.f, 0.f};
#pragma unroll
        for (int ks = 0; ks < 2; ++ks) {
            int rq = strip + ln;
            bf16x8 aq = *(bf16x8*)&q_s[rq * 64 + (((ks * 4 + quad) ^ (rq & 7)) << 3)];
#pragma unroll
            for (int nt = 0; nt < 3; ++nt) {
                int rp = nt * 16 + ln;
                bf16x8 bp = *(bf16x8*)&rel_s[rp * 64 + (((ks * 4 + quad) ^ (rp & 7)) << 3)];
                qacc[nt] = __builtin_amdgcn_mfma_f32_16x16x32_bf16(aq, bp, qacc[nt], 0, 0, 0);
            }
        }
#pragma unroll
        for (int nt = 0; nt < 3; ++nt) {
            int p = nt * 16 + ln;
            if (p < 33) {
#pragma unroll
                for (int reg = 0; reg < 4; ++reg)
                    qr[p * 64 + strip + quad * 4 + reg] = qacc[nt][reg];
            }
        }
    }
    __syncthreads();   // qr complete; rel_s reads done (t_s overlay safe)

    const int iloc = strip + ln;
    const float cL = qr[iloc] + snb;             // far-left bias  (p=0)
    const float cR = qr[32 * 64 + iloc] + snb;   // far-right      (p=32)

    bf16x8 bq[2];
#pragma unroll
    for (int ks = 0; ks < 2; ++ks)
        bq[ks] = *(bf16x8*)&q_s[iloc * 64 + (((ks * 4 + quad) ^ (iloc & 7)) << 3)];

    float Lsum = 0.f;
    f32x4 o_acc[4];
#pragma unroll
    for (int nt = 0; nt < 4; ++nt) o_acc[nt] = (f32x4){0.f, 0.f, 0.f, 0.f};

    for (int jt = 0; jt < 16; ++jt) {
        const int j0 = jt * 64;
        __syncthreads();   // prev-iter k_s/v_s readers done
#pragma unroll
        for (int c = 0; c < 2; ++c) {
            int r0 = w * 16 + c * 8;
            int gr = r0 + ri;
            gll16(kplane + (size_t)(j0 + gr) * 64 + scol, &k_s[r0 * 64]);
            gll16(vplane + (size_t)gr * 1024 + j0 + scol, &v_s[r0 * 64]);
        }
        __syncthreads();

        // S^T: sacc[mj] = D[j = mj*16+quad*4+reg][i = ln]
        f32x4 sacc[4];
#pragma unroll
        for (int mj = 0; mj < 4; ++mj) sacc[mj] = (f32x4){0.f, 0.f, 0.f, 0.f};
#pragma unroll
        for (int ks = 0; ks < 2; ++ks) {
#pragma unroll
            for (int mj = 0; mj < 4; ++mj) {
                int rk = mj * 16 + ln;
                bf16x8 ak = *(bf16x8*)&k_s[rk * 64 + (((ks * 4 + quad) ^ (rk & 7)) << 3)];
                sacc[mj] = __builtin_amdgcn_mfma_f32_16x16x32_bf16(ak, bq[ks], sacc[mj], 0, 0, 0);
            }
        }

        // epilogue: t = relu(s + bias)^2, pack 4 consecutive j -> b64 write
        const int d0 = j0 - i0;
        if (d0 <= -128 || d0 >= 128) {
            const float c = (d0 < 0) ? cL : cR;    // per-lane constant
#pragma unroll
            for (int mj = 0; mj < 4; ++mj) {
                float tv[4];
#pragma unroll
                for (int reg = 0; reg < 4; ++reg) {
                    float t = fmaxf(sacc[mj][reg] + c, 0.f);
                    t = t * t;
                    Lsum += t;
                    tv[reg] = t;
                }
                u32x2 pk;
                pk.x = pack2(tv[0], tv[1]);
                pk.y = pack2(tv[2], tv[3]);
                int jl = mj * 16 + quad * 4;
                int chunk = (jl >> 3) ^ (iloc & 7);
                *(u32x2*)&t_s[iloc * 64 + (chunk << 3) + (quad & 1) * 4] = pk;
            }
        } else {
#pragma unroll
            for (int mj = 0; mj < 4; ++mj) {
                int jbase = j0 + mj * 16 + quad * 4;
                float tv[4];
#pragma unroll
                for (int reg = 0; reg < 4; ++reg) {
                    int dlt = jbase + reg - (i0 + iloc);
                    int p = min(max(dlt, -16), 16) + 16;
                    float t = fmaxf(sacc[mj][reg] + qr[p * 64 + iloc] + snb, 0.f);
                    t = t * t;
                    Lsum += t;
                    tv[reg] = t;
                }
                u32x2 pk;
                pk.x = pack2(tv[0], tv[1]);
                pk.y = pack2(tv[2], tv[3]);
                int jl = mj * 16 + quad * 4;
                int chunk = (jl >> 3) ^ (iloc & 7);
                *(u32x2*)&t_s[iloc * 64 + (chunk << 3) + (quad & 1) * 4] = pk;
            }
        }

        // PV: A = t rows (same-wave writes; in-order DS within wave)
#pragma unroll
        for (int ks = 0; ks < 2; ++ks) {
            bf16x8 at = *(bf16x8*)&t_s[iloc * 64 + (((ks * 4 + quad) ^ (iloc & 7)) << 3)];
#pragma unroll
            for (int nt = 0; nt < 4; ++nt) {
                int rv = nt * 16 + ln;
                bf16x8 bv = *(bf16x8*)&v_s[rv * 64 + (((ks * 4 + quad) ^ (rv & 7)) << 3)];
                o_acc[nt] = __builtin_amdgcn_mfma_f32_16x16x32_bf16(at, bv, o_acc[nt], 0, 0, 0);
            }
        }
    }

    Lsum += __shfl_xor(Lsum, 16);
    Lsum += __shfl_xor(Lsum, 32);
    float Linv = 1.f / (Lsum + 1e-8f);

    const int b = bh >> 4, h = bh & 15;
#pragma unroll
    for (int reg = 0; reg < 4; ++reg) {
        int ig = i0 + strip + quad * 4 + reg;
        float li = __shfl(Linv, quad * 4 + reg);
#pragma unroll
        for (int nt = 0; nt < 4; ++nt) {
            int dg = nt * 16 + ln;
            ctx[((size_t)(b * 1024 + ig)) * 1024 + h * 64 + dg] =
                f2bf(o_acc[nt][reg] * li);
        }
    }
}

// ---------------------------------------------------------------------------
// Kernel 3: out = ctx @ Wo^T + bo  (M=4096, N=1024, K=1024), bf16 in, f32 out
// ---------------------------------------------------------------------------
__global__ __launch_bounds__(256) void out_gemm(
    const u16* __restrict__ A, const u16* __restrict__ W,
    const float* __restrict__ bias, float* __restrict__ out)
{
    __shared__ u16 As[128 * 64];
    __shared__ u16 Bs[128 * 64];

    const int tid  = threadIdx.x;
    const int lane = tid & 63, w = tid >> 6;
    const int quad = lane >> 4, ln = lane & 15;
    const int wrow = (w >> 1) * 64, wcol = (w & 1) * 64;
    const int row0 = blockIdx.y * 128, col0 = blockIdx.x * 128;

    const int ri = lane >> 3, ci = lane & 7;
    const int scol = (ci ^ ri) << 3;

    f32x4 acc[4][4];
#pragma unroll
    for (int i = 0; i < 4; i++)
#pragma unroll
        for (int j = 0; j < 4; j++) acc[i][j] = (f32x4){0.f, 0.f, 0.f, 0.f};

    for (int kb_i = 0; kb_i < 16; ++kb_i) {
        const int k0 = kb_i * 64;
#pragma unroll
        for (int c = 0; c < 4; ++c) {
            int r0 = c * 32 + w * 8;
            int gr = r0 + ri;
            gll16(A + (size_t)(row0 + gr) * D_ + k0 + scol, &As[r0 * 64]);
            gll16(W + (size_t)(col0 + gr) * D_ + k0 + scol, &Bs[r0 * 64]);
        }
        __syncthreads();
#pragma unroll
        for (int ks = 0; ks < 2; ++ks) {
            bf16x8 af[4], bfr[4];
#pragma unroll
            for (int mt = 0; mt < 4; ++mt) {
                int r = wrow + mt * 16 + ln;
                af[mt] = *(bf16x8*)&As[r * 64 + (((ks * 4 + quad) ^ (r & 7)) << 3)];
            }
#pragma unroll
            for (int nt = 0; nt < 4; ++nt) {
                int r = wcol + nt * 16 + ln;
                bfr[nt] = *(bf16x8*)&Bs[r * 64 + (((ks * 4 + quad) ^ (r & 7)) << 3)];
            }
#pragma unroll
            for (int mt = 0; mt < 4; ++mt)
#pragma unroll
                for (int nt = 0; nt < 4; ++nt)
                    acc[mt][nt] = __builtin_amdgcn_mfma_f32_16x16x32_bf16(
                        af[mt], bfr[nt], acc[mt][nt], 0, 0, 0);
        }
        __syncthreads();
    }
#pragma unroll
    for (int mt = 0; mt < 4; ++mt) {
#pragma unroll
        for (int nt = 0; nt < 4; ++nt) {
            int n = col0 + wcol + nt * 16 + ln;
            float bv = bias[n];
#pragma unroll
            for (int reg = 0; reg < 4; ++reg) {
                int m = row0 + wrow + mt * 16 + quad * 4 + reg;
                out[(size_t)m * D_ + n] = acc[mt][nt][reg] + bv;
            }
        }
    }
}

// ---------------------------------------------------------------------------
extern "C" void kernel_launch(void* const* d_in, const int* in_sizes, int n_in,
                              void* d_out, int out_size, void* d_ws, size_t ws_size,
                              hipStream_t stream)
{
    const float* iQ  = (const float*)d_in[0];
    const float* Wa  = (const float*)d_in[1];
    const float* ba  = (const float*)d_in[2];
    const float* rel = (const float*)d_in[3];
    const float* snb = (const float*)d_in[4];
    const float* Wo  = (const float*)d_in[5];
    const float* bo  = (const float*)d_in[6];
    float* out = (float*)d_out;

    const size_t NQ = (size_t)B_ * S_ * D_;     // 4M
    const size_t NWA = (size_t)3 * D_ * D_;     // 3M
    const size_t NWO = (size_t)D_ * D_;         // 1M
    const size_t PLANE = (size_t)B_ * H_ * S_ * AD_;  // 4M

    u16* iQbf = (u16*)d_ws;          // reused as ctx after qkv_gemm
    u16* Wabf = iQbf + NQ;
    u16* Wobf = Wabf + NWA;
    u16* qbuf = Wobf + NWO;
    u16* kbuf = qbuf + PLANE;
    u16* vbuf = kbuf + PLANE;
    u16* ctx  = iQbf;                // alias: iQbf dead after qkv_gemm

    conv_bf16<<<4096, 256, 0, stream>>>(iQ, Wa, Wo, iQbf, Wabf, Wobf,
                                        (int)NQ, (int)NWA);
    qkv_gemm<<<dim3(24, 32), 256, 0, stream>>>(iQbf, Wabf, ba, qbuf, kbuf, vbuf);
    attn_kernel<<<dim3(1024), 256, 0, stream>>>(qbuf, kbuf, vbuf, rel, snb, ctx);
    out_gemm<<<dim3(8, 32), 256, 0, stream>>>(ctx, Wobf, bo, out);
}